// Round 2
// baseline (460.101 us; speedup 1.0000x reference)
//
#include <hip/hip_runtime.h>
#include <hip/hip_bf16.h>

// CapsuleLayer dynamic routing, MI355X.
// B=32,N=2048,D=32 inputs; C=64,V=32 output caps; 3 routing rounds.
// u_hat computed once via bf16 MFMA -> ws (bf16, 256MB, L3-resident);
// each routing round = one fused pass over u_hat (agree -> softmax -> s-accum),
// using linearity of agreement: b_logits = u_hat . (v1+v2+...).
// Round 2 change: uhat stores staged through wave-private LDS so global
// writes are dwordx4 full-line (was: 256 scattered 2B stores/thread, 1.5x
// write amplification, 24% HBM).

#define B_ 32
#define N_ 2048
#define D_ 32
#define C_ 64
#define V_ 32

typedef __attribute__((ext_vector_type(4))) float f32x4;
typedef __attribute__((ext_vector_type(4))) int i32x4;
typedef __bf16 bf16x8 __attribute__((ext_vector_type(8)));

__device__ __forceinline__ unsigned f2bf1(float f) {
  unsigned u = __builtin_bit_cast(unsigned, f);
  return (u + 0x7FFFu + ((u >> 16) & 1u)) >> 16;  // RNE
}
__device__ __forceinline__ float bf2f(unsigned h) {
  unsigned u = h << 16;
  return __builtin_bit_cast(float, u);
}

// Pass 0: u_hat[b,n,c,v] = sum_d x[b,n,d]*W[n,c,v,d], stored bf16 as [b][n][p], p=c*32+v.
// One block per n, 4 waves; wave owns p-range of 512. MFMA accs staged in
// wave-private LDS (quarter chunks of 128 p), flushed as 128B/lane dwordx4.
__global__ __launch_bounds__(256) void uhat_kernel(const float* __restrict__ x,
                                                   const float* __restrict__ W,
                                                   unsigned short* __restrict__ uh) {
  const int n = blockIdx.x;
  const int wave = threadIdx.x >> 6;
  const int l = threadIdx.x & 63;
  const int l16 = l & 15, kg = l >> 4;  // A/B frag: row/col = l16, k = kg*8 + i

  // Row stride 132 shorts = 66 dwords; 66%32=2 and rows are kg*4+j so the 4
  // quarter-wave writer groups sit 8 banks apart -> conflict-free b16 writes.
  __shared__ unsigned short lds[4][32 * 132];
  unsigned short* wlds = lds[wave];

  bf16x8 a[2];
#pragma unroll
  for (int mt = 0; mt < 2; ++mt) {
    const float* xp = x + (((size_t)(mt * 16 + l16)) * N_ + n) * D_ + kg * 8;
    f32x4 x0 = *(const f32x4*)xp;
    f32x4 x1 = *(const f32x4*)(xp + 4);
    i32x4 af;
    af[0] = f2bf1(x0[0]) | (f2bf1(x0[1]) << 16);
    af[1] = f2bf1(x0[2]) | (f2bf1(x0[3]) << 16);
    af[2] = f2bf1(x1[0]) | (f2bf1(x1[1]) << 16);
    af[3] = f2bf1(x1[2]) | (f2bf1(x1[3]) << 16);
    a[mt] = __builtin_bit_cast(bf16x8, af);
  }
  const f32x4 zero = {0.f, 0.f, 0.f, 0.f};

  for (int q = 0; q < 4; ++q) {
#pragma unroll
    for (int pt8 = 0; pt8 < 8; ++pt8) {
      const int p = (wave * 32 + q * 8 + pt8) * 16 + l16;
      const float* wp = W + ((size_t)n * 2048 + p) * D_ + kg * 8;
      f32x4 w0 = *(const f32x4*)wp;
      f32x4 w1 = *(const f32x4*)(wp + 4);
      i32x4 bv;
      bv[0] = f2bf1(w0[0]) | (f2bf1(w0[1]) << 16);
      bv[1] = f2bf1(w0[2]) | (f2bf1(w0[3]) << 16);
      bv[2] = f2bf1(w1[0]) | (f2bf1(w1[1]) << 16);
      bv[3] = f2bf1(w1[2]) | (f2bf1(w1[3]) << 16);
      bf16x8 bfrag = __builtin_bit_cast(bf16x8, bv);
#pragma unroll
      for (int mt = 0; mt < 2; ++mt) {
        f32x4 acc = __builtin_amdgcn_mfma_f32_16x16x32_bf16(a[mt], bfrag, zero, 0, 0, 0);
#pragma unroll
        for (int j = 0; j < 4; ++j) {
          const int br = mt * 16 + kg * 4 + j;  // C/D: row=(l>>4)*4+j, col=l&15
          wlds[br * 132 + pt8 * 16 + l16] = (unsigned short)f2bf1(acc[j]);
        }
      }
    }
    // all LDS writes of this quarter done before cross-lane readback
    asm volatile("s_waitcnt lgkmcnt(0)" ::: "memory");
    __builtin_amdgcn_sched_barrier(0);
    const int br = l >> 1, half = l & 1;
    const unsigned short* src = wlds + br * 132 + half * 64;
    unsigned short* dst = uh + ((size_t)br * N_ + n) * 2048 +
                          (size_t)((wave * 32 + q * 8) * 16) + half * 64;
#pragma unroll
    for (int i = 0; i < 8; ++i) {
      i32x4 vv = *(const i32x4*)(src + i * 8);
      *(i32x4*)(dst + i * 8) = vv;
    }
    // WAR fence: readback complete before next quarter overwrites the tile
    asm volatile("s_waitcnt lgkmcnt(0)" ::: "memory");
    __builtin_amdgcn_sched_barrier(0);
  }
}

// Routing pass: s[b,c,v] = sum_n softmax_c(u_hat[b,n,:,:].vsum[b,:,:])[c] * u_hat[b,n,c,v]
// wave lane l == c. Block = 4 waves x 16 n, same b. Partials (no atomics) to ws.
template <int ROUND>
__global__ __launch_bounds__(256) void routing_kernel(const unsigned short* __restrict__ uh,
                                                      const float* __restrict__ vsum,
                                                      float* __restrict__ part) {
  const int b = blockIdx.x >> 5;  // 32 chunks per b
  const int chunk = blockIdx.x & 31;
  const int wave = threadIdx.x >> 6;
  const int l = threadIdx.x & 63;  // = c

  float vs[32];
  if (ROUND >= 2) {
    const f32x4* vp = (const f32x4*)(vsum + ((size_t)b * 64 + l) * 32);
#pragma unroll
    for (int i = 0; i < 8; ++i) {
      f32x4 t = vp[i];
      vs[4 * i] = t[0]; vs[4 * i + 1] = t[1]; vs[4 * i + 2] = t[2]; vs[4 * i + 3] = t[3];
    }
  }
  float sacc[32];
#pragma unroll
  for (int v = 0; v < 32; ++v) sacc[v] = 0.f;

  const int n0 = chunk * 64 + wave * 16;
  for (int ni = 0; ni < 16; ++ni) {
    const int n = n0 + ni;
    const i32x4* up = (const i32x4*)(uh + ((size_t)b * N_ + n) * 2048 + l * 32);
    i32x4 qs0 = up[0], qs1 = up[1], qs2 = up[2], qs3 = up[3];
    float u[32];
#pragma unroll
    for (int i = 0; i < 4; ++i) {
      unsigned v0 = (unsigned)qs0[i], v1 = (unsigned)qs1[i], v2 = (unsigned)qs2[i], v3 = (unsigned)qs3[i];
      u[0 + 2 * i] = bf2f(v0 & 0xffffu);  u[0 + 2 * i + 1] = bf2f(v0 >> 16);
      u[8 + 2 * i] = bf2f(v1 & 0xffffu);  u[8 + 2 * i + 1] = bf2f(v1 >> 16);
      u[16 + 2 * i] = bf2f(v2 & 0xffffu); u[16 + 2 * i + 1] = bf2f(v2 >> 16);
      u[24 + 2 * i] = bf2f(v3 & 0xffffu); u[24 + 2 * i + 1] = bf2f(v3 >> 16);
    }
    float r;
    if (ROUND >= 2) {
      float br = 0.f;
#pragma unroll
      for (int v = 0; v < 32; ++v) br = fmaf(u[v], vs[v], br);
      float m = br;
#pragma unroll
      for (int off = 32; off; off >>= 1) m = fmaxf(m, __shfl_xor(m, off, 64));
      float e = __expf(br - m);
      float den = e;
#pragma unroll
      for (int off = 32; off; off >>= 1) den += __shfl_xor(den, off, 64);
      r = e / den;
    } else {
      r = 1.0f / 64.0f;  // softmax of zeros
    }
#pragma unroll
    for (int v = 0; v < 32; ++v) sacc[v] = fmaf(r, u[v], sacc[v]);
  }

  __shared__ float red[4][64][33];  // +1 pad: conflict-free
#pragma unroll
  for (int v = 0; v < 32; ++v) red[wave][l][v] = sacc[v];
  __syncthreads();
  const int t = threadIdx.x;
  f32x4 o0, o1;
#pragma unroll
  for (int i = 0; i < 4; ++i) {
    const int e0 = t * 8 + i, e1 = t * 8 + 4 + i;
    o0[i] = red[0][e0 >> 5][e0 & 31] + red[1][e0 >> 5][e0 & 31] +
            red[2][e0 >> 5][e0 & 31] + red[3][e0 >> 5][e0 & 31];
    o1[i] = red[0][e1 >> 5][e1 & 31] + red[1][e1 >> 5][e1 & 31] +
            red[2][e1 >> 5][e1 & 31] + red[3][e1 >> 5][e1 & 31];
  }
  float* pp = part + ((size_t)blockIdx.x) * 2048 + t * 8;
  *(f32x4*)pp = o0;
  *(f32x4*)(pp + 4) = o1;
}

// Reduce partials -> s, squash -> v. Writes v to out; maintains vsum for agreement.
template <int ROUND>
__global__ __launch_bounds__(256) void squash_kernel(const float* __restrict__ part,
                                                     float* __restrict__ vsum,
                                                     float* __restrict__ out) {
  const int t = blockIdx.x * 256 + threadIdx.x;  // 0..65535 = b*2048 + c*32 + v
  const int b = t >> 11;
  const int e = t & 2047;
  float sv = 0.f;
#pragma unroll
  for (int k = 0; k < 32; ++k) sv += part[((size_t)(b * 32 + k)) * 2048 + e];
  float sq = sv * sv;
#pragma unroll
  for (int off = 16; off; off >>= 1) sq += __shfl_xor(sq, off, 64);  // sum over v (32-lane groups)
  float scale = (sq / (1.f + sq)) * rsqrtf(sq + 1e-9f);
  float val = sv * scale;
  out[t] = val;
  if (ROUND == 1) vsum[t] = val;
  else if (ROUND == 2) vsum[t] += val;
}

extern "C" void kernel_launch(void* const* d_in, const int* in_sizes, int n_in,
                              void* d_out, int out_size, void* d_ws, size_t ws_size,
                              hipStream_t stream) {
  const float* x = (const float*)d_in[0];  // [B,N,D]
  const float* W = (const float*)d_in[1];  // [1,N,C,V,D]
  float* out = (float*)d_out;              // [B,1,C,V,1] = 65536 fp32

  const size_t UH_BYTES = (size_t)B_ * N_ * C_ * V_ * 2;  // 268435456
  const size_t PART_BYTES = (size_t)B_ * 32 * 2048 * 4;   // 8388608
  const size_t VSUM_BYTES = (size_t)B_ * C_ * V_ * 4;     // 262144
  if (ws_size < UH_BYTES + PART_BYTES + VSUM_BYTES) return;  // can't run

  unsigned short* uh = (unsigned short*)d_ws;
  float* part = (float*)((char*)d_ws + UH_BYTES);
  float* vsum = (float*)((char*)d_ws + UH_BYTES + PART_BYTES);

  uhat_kernel<<<N_, 256, 0, stream>>>(x, W, uh);
  routing_kernel<1><<<B_ * 32, 256, 0, stream>>>(uh, vsum, part);
  squash_kernel<1><<<256, 256, 0, stream>>>(part, vsum, out);
  routing_kernel<2><<<B_ * 32, 256, 0, stream>>>(uh, vsum, part);
  squash_kernel<2><<<256, 256, 0, stream>>>(part, vsum, out);
  routing_kernel<3><<<B_ * 32, 256, 0, stream>>>(uh, vsum, part);
  squash_kernel<3><<<256, 256, 0, stream>>>(part, vsum, out);
}

// Round 3
// 332.403 us; speedup vs baseline: 1.3842x; 1.3842x over previous
//
#include <hip/hip_runtime.h>
#include <hip/hip_bf16.h>

// CapsuleLayer dynamic routing, MI355X.
// B=32,N=2048,D=32 inputs; C=64,V=32 output caps; 3 routing rounds.
// u_hat computed once via bf16 MFMA -> ws (bf16, 256MB, L3-resident);
// each routing round = one fused pass over u_hat (agree -> softmax -> s-accum),
// using linearity of agreement: b_logits = u_hat . (v1+v2+...).
// Round 3 change: uh layout transposed to [n][b][p]. The old [b][n][p] put a
// wave's 32 concurrently-dirty store lines at stride 8MB (same L2 set, 16-way)
// -> partial-dirty evictions, RMW at HBM (WRITE 1.48x ideal), vmcnt backpressure,
// waves 99% stalled at 2TB/s. New layout: each block writes one contiguous
// 256KB region; flush rows 4KB apart = consecutive sets.

#define B_ 32
#define N_ 2048
#define D_ 32
#define C_ 64
#define V_ 32

typedef __attribute__((ext_vector_type(4))) float f32x4;
typedef __attribute__((ext_vector_type(4))) int i32x4;
typedef __bf16 bf16x8 __attribute__((ext_vector_type(8)));

__device__ __forceinline__ unsigned f2bf1(float f) {
  unsigned u = __builtin_bit_cast(unsigned, f);
  return (u + 0x7FFFu + ((u >> 16) & 1u)) >> 16;  // RNE
}
__device__ __forceinline__ float bf2f(unsigned h) {
  unsigned u = h << 16;
  return __builtin_bit_cast(float, u);
}

// Pass 0: u_hat[n][b][p] (p=c*32+v), bf16. One block per n, 4 waves; wave owns
// 512 p. 8 phases of 4 p-tiles: MFMA -> wave-private LDS (stride-68 rows:
// 8-bank partition per kg group on writes) -> 16B/lane contiguous stores.
__global__ __launch_bounds__(256) void uhat_kernel(const float* __restrict__ x,
                                                   const float* __restrict__ W,
                                                   unsigned short* __restrict__ uh) {
  const int n = blockIdx.x;
  const int wave = threadIdx.x >> 6;
  const int l = threadIdx.x & 63;
  const int l16 = l & 15, kg = l >> 4;  // A/B frag: row/col = l16, k = kg*8 + i

  __shared__ unsigned short lds[4][32 * 68];
  unsigned short* wlds = lds[wave];

  bf16x8 a[2];
#pragma unroll
  for (int mt = 0; mt < 2; ++mt) {
    const float* xp = x + (((size_t)(mt * 16 + l16)) * N_ + n) * D_ + kg * 8;
    f32x4 x0 = *(const f32x4*)xp;
    f32x4 x1 = *(const f32x4*)(xp + 4);
    i32x4 af;
    af[0] = f2bf1(x0[0]) | (f2bf1(x0[1]) << 16);
    af[1] = f2bf1(x0[2]) | (f2bf1(x0[3]) << 16);
    af[2] = f2bf1(x1[0]) | (f2bf1(x1[1]) << 16);
    af[3] = f2bf1(x1[2]) | (f2bf1(x1[3]) << 16);
    a[mt] = __builtin_bit_cast(bf16x8, af);
  }
  const f32x4 zero = {0.f, 0.f, 0.f, 0.f};
  const int br_f = l >> 1, half = l & 1;  // flush roles: 2 lanes per b-row

  for (int ph = 0; ph < 8; ++ph) {
#pragma unroll
    for (int pt4 = 0; pt4 < 4; ++pt4) {
      const int p = wave * 512 + ph * 64 + pt4 * 16 + l16;
      const float* wp = W + ((size_t)n * 2048 + p) * D_ + kg * 8;
      f32x4 w0 = *(const f32x4*)wp;
      f32x4 w1 = *(const f32x4*)(wp + 4);
      i32x4 bv;
      bv[0] = f2bf1(w0[0]) | (f2bf1(w0[1]) << 16);
      bv[1] = f2bf1(w0[2]) | (f2bf1(w0[3]) << 16);
      bv[2] = f2bf1(w1[0]) | (f2bf1(w1[1]) << 16);
      bv[3] = f2bf1(w1[2]) | (f2bf1(w1[3]) << 16);
      bf16x8 bfrag = __builtin_bit_cast(bf16x8, bv);
#pragma unroll
      for (int mt = 0; mt < 2; ++mt) {
        f32x4 acc = __builtin_amdgcn_mfma_f32_16x16x32_bf16(a[mt], bfrag, zero, 0, 0, 0);
#pragma unroll
        for (int j = 0; j < 4; ++j) {
          const int br = mt * 16 + kg * 4 + j;  // C/D: row=(l>>4)*4+j, col=l&15
          wlds[br * 68 + pt4 * 16 + l16] = (unsigned short)f2bf1(acc[j]);
        }
      }
    }
    // all LDS writes of this phase complete before cross-lane readback
    asm volatile("s_waitcnt lgkmcnt(0)" ::: "memory");
    __builtin_amdgcn_sched_barrier(0);
    {
      const unsigned short* src = wlds + br_f * 68 + half * 32;
      unsigned short* dst = uh + ((size_t)n * 32 + br_f) * 2048 +
                            (size_t)(wave * 512 + ph * 64 + half * 32);
      i32x4 v0 = *(const i32x4*)(src + 0);
      i32x4 v1 = *(const i32x4*)(src + 8);
      i32x4 v2 = *(const i32x4*)(src + 16);
      i32x4 v3 = *(const i32x4*)(src + 24);
      *(i32x4*)(dst + 0) = v0;
      *(i32x4*)(dst + 8) = v1;
      *(i32x4*)(dst + 16) = v2;
      *(i32x4*)(dst + 24) = v3;
    }
    // WAR fence: readback complete before next phase overwrites the tile
    asm volatile("s_waitcnt lgkmcnt(0)" ::: "memory");
    __builtin_amdgcn_sched_barrier(0);
  }
}

// Routing pass: s[b,c,v] = sum_n softmax_c(u_hat[b,n,:,:].vsum[b,:,:])[c] * u_hat[b,n,c,v]
// wave lane l == c. Block = 4 waves x 16 n, same b. Partials (no atomics) to ws.
template <int ROUND>
__global__ __launch_bounds__(256) void routing_kernel(const unsigned short* __restrict__ uh,
                                                      const float* __restrict__ vsum,
                                                      float* __restrict__ part) {
  const int b = blockIdx.x >> 5;  // 32 chunks per b
  const int chunk = blockIdx.x & 31;
  const int wave = threadIdx.x >> 6;
  const int l = threadIdx.x & 63;  // = c

  float vs[32];
  if (ROUND >= 2) {
    const f32x4* vp = (const f32x4*)(vsum + ((size_t)b * 64 + l) * 32);
#pragma unroll
    for (int i = 0; i < 8; ++i) {
      f32x4 t = vp[i];
      vs[4 * i] = t[0]; vs[4 * i + 1] = t[1]; vs[4 * i + 2] = t[2]; vs[4 * i + 3] = t[3];
    }
  }
  float sacc[32];
#pragma unroll
  for (int v = 0; v < 32; ++v) sacc[v] = 0.f;

  const int n0 = chunk * 64 + wave * 16;
  for (int ni = 0; ni < 16; ++ni) {
    const int n = n0 + ni;
    const i32x4* up = (const i32x4*)(uh + ((size_t)n * 32 + b) * 2048 + l * 32);
    i32x4 qs0 = up[0], qs1 = up[1], qs2 = up[2], qs3 = up[3];
    float u[32];
#pragma unroll
    for (int i = 0; i < 4; ++i) {
      unsigned v0 = (unsigned)qs0[i], v1 = (unsigned)qs1[i], v2 = (unsigned)qs2[i], v3 = (unsigned)qs3[i];
      u[0 + 2 * i] = bf2f(v0 & 0xffffu);  u[0 + 2 * i + 1] = bf2f(v0 >> 16);
      u[8 + 2 * i] = bf2f(v1 & 0xffffu);  u[8 + 2 * i + 1] = bf2f(v1 >> 16);
      u[16 + 2 * i] = bf2f(v2 & 0xffffu); u[16 + 2 * i + 1] = bf2f(v2 >> 16);
      u[24 + 2 * i] = bf2f(v3 & 0xffffu); u[24 + 2 * i + 1] = bf2f(v3 >> 16);
    }
    float r;
    if (ROUND >= 2) {
      float br = 0.f;
#pragma unroll
      for (int v = 0; v < 32; ++v) br = fmaf(u[v], vs[v], br);
      float m = br;
#pragma unroll
      for (int off = 32; off; off >>= 1) m = fmaxf(m, __shfl_xor(m, off, 64));
      float e = __expf(br - m);
      float den = e;
#pragma unroll
      for (int off = 32; off; off >>= 1) den += __shfl_xor(den, off, 64);
      r = e / den;
    } else {
      r = 1.0f / 64.0f;  // softmax of zeros
    }
#pragma unroll
    for (int v = 0; v < 32; ++v) sacc[v] = fmaf(r, u[v], sacc[v]);
  }

  __shared__ float red[4][64][33];  // +1 pad: conflict-free
#pragma unroll
  for (int v = 0; v < 32; ++v) red[wave][l][v] = sacc[v];
  __syncthreads();
  const int t = threadIdx.x;
  f32x4 o0, o1;
#pragma unroll
  for (int i = 0; i < 4; ++i) {
    const int e0 = t * 8 + i, e1 = t * 8 + 4 + i;
    o0[i] = red[0][e0 >> 5][e0 & 31] + red[1][e0 >> 5][e0 & 31] +
            red[2][e0 >> 5][e0 & 31] + red[3][e0 >> 5][e0 & 31];
    o1[i] = red[0][e1 >> 5][e1 & 31] + red[1][e1 >> 5][e1 & 31] +
            red[2][e1 >> 5][e1 & 31] + red[3][e1 >> 5][e1 & 31];
  }
  float* pp = part + ((size_t)blockIdx.x) * 2048 + t * 8;
  *(f32x4*)pp = o0;
  *(f32x4*)(pp + 4) = o1;
}

// Reduce partials -> s, squash -> v. Writes v to out; maintains vsum for agreement.
template <int ROUND>
__global__ __launch_bounds__(256) void squash_kernel(const float* __restrict__ part,
                                                     float* __restrict__ vsum,
                                                     float* __restrict__ out) {
  const int t = blockIdx.x * 256 + threadIdx.x;  // 0..65535 = b*2048 + c*32 + v
  const int b = t >> 11;
  const int e = t & 2047;
  float sv = 0.f;
#pragma unroll
  for (int k = 0; k < 32; ++k) sv += part[((size_t)(b * 32 + k)) * 2048 + e];
  float sq = sv * sv;
#pragma unroll
  for (int off = 16; off; off >>= 1) sq += __shfl_xor(sq, off, 64);  // sum over v (32-lane groups)
  float scale = (sq / (1.f + sq)) * rsqrtf(sq + 1e-9f);
  float val = sv * scale;
  out[t] = val;
  if (ROUND == 1) vsum[t] = val;
  else if (ROUND == 2) vsum[t] += val;
}

extern "C" void kernel_launch(void* const* d_in, const int* in_sizes, int n_in,
                              void* d_out, int out_size, void* d_ws, size_t ws_size,
                              hipStream_t stream) {
  const float* x = (const float*)d_in[0];  // [B,N,D]
  const float* W = (const float*)d_in[1];  // [1,N,C,V,D]
  float* out = (float*)d_out;              // [B,1,C,V,1] = 65536 fp32

  const size_t UH_BYTES = (size_t)B_ * N_ * C_ * V_ * 2;  // 268435456
  const size_t PART_BYTES = (size_t)B_ * 32 * 2048 * 4;   // 8388608
  const size_t VSUM_BYTES = (size_t)B_ * C_ * V_ * 4;     // 262144
  if (ws_size < UH_BYTES + PART_BYTES + VSUM_BYTES) return;  // can't run

  unsigned short* uh = (unsigned short*)d_ws;
  float* part = (float*)((char*)d_ws + UH_BYTES);
  float* vsum = (float*)((char*)d_ws + UH_BYTES + PART_BYTES);

  uhat_kernel<<<N_, 256, 0, stream>>>(x, W, uh);
  routing_kernel<1><<<B_ * 32, 256, 0, stream>>>(uh, vsum, part);
  squash_kernel<1><<<256, 256, 0, stream>>>(part, vsum, out);
  routing_kernel<2><<<B_ * 32, 256, 0, stream>>>(uh, vsum, part);
  squash_kernel<2><<<256, 256, 0, stream>>>(part, vsum, out);
  routing_kernel<3><<<B_ * 32, 256, 0, stream>>>(uh, vsum, part);
  squash_kernel<3><<<256, 256, 0, stream>>>(part, vsum, out);
}